// Round 1
// baseline (724.282 us; speedup 1.0000x reference)
//
#include <hip/hip_runtime.h>

// MPLayer v6: CSR index-permutation (sort edge IDs, not payloads).
//   deg  = histogram(dst)                       (int atomics)
//   cursor = exclusive_scan(deg)                (3-kernel parallel scan)
//   pair[slot] = {src[e], e}                    (8B scattered write, L2-resident)
//   z_csr: per-node reduce gathering edge_x[e] directly (128B lines, read once)
//          + W_pre matvec (readlane weights)
//   h_upd: W_upd matvec (readlane weights)
// vs v5: removes the 205MB scattered rows[] write + 205MB re-read; ws 238->40MB.
// Fallback (ws too small): R1 atomic scatter + same epilogues.

#define N_NODES 100000
#define N_EDGES 1600000
#define ND 32
#define ED 32
#define OD 32
#define ZD 64
#define NTILE 98   // ceil(N_NODES/1024)

__device__ inline float bcast(float v, int lane) {
    return __uint_as_float(__builtin_amdgcn_readlane(__float_as_uint(v), lane));
}

// ---------- CSR build ----------
__global__ __launch_bounds__(256) void hist(const int* __restrict__ dst,
                                            int* __restrict__ cnt) {
    int e = blockIdx.x * 256 + threadIdx.x;
    if (e < N_EDGES) atomicAdd(&cnt[dst[e]], 1);
}

__global__ __launch_bounds__(1024) void scan_part(const int* __restrict__ cnt,
                                                  int* __restrict__ part) {
    __shared__ int s[1024];
    int i = blockIdx.x * 1024 + threadIdx.x;
    s[threadIdx.x] = (i < N_NODES) ? cnt[i] : 0;
    __syncthreads();
    for (int off = 512; off > 0; off >>= 1) {
        if (threadIdx.x < off) s[threadIdx.x] += s[threadIdx.x + off];
        __syncthreads();
    }
    if (threadIdx.x == 0) part[blockIdx.x] = s[0];
}

__global__ void scan_top(int* part) {   // 1 block, 128 threads, NTILE<=128
    __shared__ int s[128];
    int v = (threadIdx.x < NTILE) ? part[threadIdx.x] : 0;
    s[threadIdx.x] = v;
    __syncthreads();
    for (int off = 1; off < 128; off <<= 1) {
        int u = (threadIdx.x >= off) ? s[threadIdx.x - off] : 0;
        __syncthreads();
        s[threadIdx.x] += u;
        __syncthreads();
    }
    if (threadIdx.x < NTILE) part[threadIdx.x] = s[threadIdx.x] - v;  // exclusive
}

__global__ __launch_bounds__(1024) void scan_local(const int* __restrict__ cnt,
                                                   const int* __restrict__ part,
                                                   int* __restrict__ cursor) {
    __shared__ int s[1024];
    int i = blockIdx.x * 1024 + threadIdx.x;
    int v = (i < N_NODES) ? cnt[i] : 0;
    s[threadIdx.x] = v;
    __syncthreads();
    for (int off = 1; off < 1024; off <<= 1) {
        int u = (threadIdx.x >= off) ? s[threadIdx.x - off] : 0;
        __syncthreads();
        s[threadIdx.x] += u;
        __syncthreads();
    }
    if (i < N_NODES) cursor[i] = part[blockIdx.x] + s[threadIdx.x] - v;
}

// ---------- permute: 1 thread per edge, IDs only ----------
__global__ __launch_bounds__(256) void permute_ids(
    const int* __restrict__ src, const int* __restrict__ dst,
    int* __restrict__ cursor, int2* __restrict__ pair)
{
    int e = blockIdx.x * 256 + threadIdx.x;
    if (e >= N_EDGES) return;
    int pos = atomicAdd(&cursor[dst[e]], 1);   // cursor ends as CSR end-pointer
    pair[pos] = make_int2(src[e], e);          // 8B scattered store, buf is L2-sized
}

// ---------- fused aggregate + z (CSR path) ----------
__global__ __launch_bounds__(256, 1) void z_csr(
    const float* __restrict__ node_x, const float* __restrict__ edge_x,
    const float* __restrict__ z_init,
    const float* __restrict__ W_pre, const float* __restrict__ b_pre,
    const int* __restrict__ cnt, const int* __restrict__ cursor,  // cursor = end
    const int2* __restrict__ pair, float* __restrict__ zbuf)
{
    const int l = threadIdx.x & 63;
    float Wp[ZD];
    #pragma unroll
    for (int k = 0; k < ZD; ++k) Wp[k] = W_pre[k * ZD + l];
    const float bp = b_pre[l];

    int w  = (blockIdx.x * 256 + threadIdx.x) >> 6;
    int nw = (gridDim.x * 256) >> 6;
    for (int n = w; n < N_NODES; n += nw) {
        int dg = cnt[n];
        float z;
        if (dg > 0) {
            int end = cursor[n];
            int j = end - dg;
            float acc = 0.0f;
            for (; j + 4 <= end; j += 4) {          // 8 x 128B lines in flight
                int2 p0 = pair[j], p1 = pair[j+1], p2 = pair[j+2], p3 = pair[j+3];
                float v0 = (l < ND) ? node_x[(long)p0.x * ND + l]
                                    : edge_x[(long)p0.y * ED + (l - ND)];
                float v1 = (l < ND) ? node_x[(long)p1.x * ND + l]
                                    : edge_x[(long)p1.y * ED + (l - ND)];
                float v2 = (l < ND) ? node_x[(long)p2.x * ND + l]
                                    : edge_x[(long)p2.y * ED + (l - ND)];
                float v3 = (l < ND) ? node_x[(long)p3.x * ND + l]
                                    : edge_x[(long)p3.y * ED + (l - ND)];
                acc += v0 + v1 + v2 + v3;
            }
            for (; j < end; ++j) {
                int2 p0 = pair[j];
                acc += (l < ND) ? node_x[(long)p0.x * ND + l]
                                : edge_x[(long)p0.y * ED + (l - ND)];
            }
            float a0 = (float)dg * bp, a1 = 0.0f;
            #pragma unroll
            for (int k = 0; k < ZD; k += 2) {
                a0 += bcast(acc, k)     * Wp[k];
                a1 += bcast(acc, k + 1) * Wp[k + 1];
            }
            z = fmaxf(a0 + a1, 0.0f);
        } else {
            z = z_init[(long)n * ZD + l];
        }
        zbuf[(long)n * ZD + l] = z;
    }
}

// ---------- fallback: R1 atomic scatter + dense z ----------
__global__ __launch_bounds__(256) void edge_scatter(
    const float* __restrict__ node_x, const float* __restrict__ edge_x,
    const int* __restrict__ src, const int* __restrict__ dst,
    float* __restrict__ S, int* __restrict__ degI)
{
    long t = (long)blockIdx.x * 256 + threadIdx.x;
    int e = (int)(t >> 6), l = (int)(t & 63);
    if (e >= N_EDGES) return;
    int s = src[e], d = dst[e];
    float v = (l < ND) ? node_x[(long)s * ND + l] : edge_x[(long)e * ED + (l - ND)];
    atomicAdd(&S[(long)d * ZD + l], v);
    if (l == 0) atomicAdd(&degI[d], 1);
}

__global__ __launch_bounds__(256, 1) void z_dense(
    const float* __restrict__ z_init,
    const float* __restrict__ W_pre, const float* __restrict__ b_pre,
    float* __restrict__ S, const int* __restrict__ degI)
{
    const int l = threadIdx.x & 63;
    float Wp[ZD];
    #pragma unroll
    for (int k = 0; k < ZD; ++k) Wp[k] = W_pre[k * ZD + l];
    const float bp = b_pre[l];
    int w  = (blockIdx.x * 256 + threadIdx.x) >> 6;
    int nw = (gridDim.x * 256) >> 6;
    for (int n = w; n < N_NODES; n += nw) {
        int dg = degI[n];
        float sv = S[(long)n * ZD + l];
        float z;
        if (dg > 0) {
            float a0 = (float)dg * bp, a1 = 0.0f;
            #pragma unroll
            for (int k = 0; k < ZD; k += 2) {
                a0 += bcast(sv, k)     * Wp[k];
                a1 += bcast(sv, k + 1) * Wp[k + 1];
            }
            z = fmaxf(a0 + a1, 0.0f);
        } else {
            z = z_init[(long)n * ZD + l];
        }
        S[(long)n * ZD + l] = z;   // in-place: wave owns row
    }
}

// ---------- shared h update ----------
__global__ __launch_bounds__(256, 1) void h_upd(
    const float* __restrict__ node_x,
    const float* __restrict__ W_upd, const float* __restrict__ b_upd,
    const float* __restrict__ zbuf, float* __restrict__ out)
{
    const int l = threadIdx.x & 63;
    const int c = l & 31;
    float Wu[ND + ZD];   // 96
    #pragma unroll
    for (int k = 0; k < ND + ZD; ++k) Wu[k] = W_upd[k * OD + c];
    const float bu = b_upd[c];
    int w  = (blockIdx.x * 256 + threadIdx.x) >> 6;
    int nw = (gridDim.x * 256) >> 6;
    for (int n = w; n < N_NODES; n += nw) {
        float zv = zbuf[(long)n * ZD + l];
        float xv = node_x[(long)n * ND + c];
        float h0 = bu, h1 = 0.0f;
        #pragma unroll
        for (int k = 0; k < ND; k += 2) {
            h0 += bcast(xv, k)     * Wu[k];
            h1 += bcast(xv, k + 1) * Wu[k + 1];
        }
        #pragma unroll
        for (int k = 0; k < ZD; k += 2) {
            h0 += bcast(zv, k)     * Wu[ND + k];
            h1 += bcast(zv, k + 1) * Wu[ND + k + 1];
        }
        if (l < OD) out[(long)n * OD + l] = fmaxf(h0 + h1, 0.0f);
    }
}

extern "C" void kernel_launch(void* const* d_in, const int* in_sizes, int n_in,
                              void* d_out, int out_size, void* d_ws, size_t ws_size,
                              hipStream_t stream)
{
    const float* node_x = (const float*)d_in[0];
    const float* edge_x = (const float*)d_in[1];
    const float* z_init = (const float*)d_in[2];
    const float* W_pre  = (const float*)d_in[3];
    const float* b_pre  = (const float*)d_in[4];
    const float* W_upd  = (const float*)d_in[5];
    const float* b_upd  = (const float*)d_in[6];
    const int*   src    = (const int*)d_in[7];
    const int*   dst    = (const int*)d_in[8];
    float* out = (float*)d_out;

    // CSR-path ws layout: pair[E]int2 | zbuf[N*64]f | cnt[N]i | part[128]i |
    //                     cursor[N]i   (~40 MB)
    size_t need = (size_t)N_EDGES * sizeof(int2)
                + (size_t)N_NODES * ZD * sizeof(float)
                + ((size_t)2 * N_NODES + 128) * sizeof(int);

    if (ws_size >= need) {
        int2*  pair   = (int2*)d_ws;
        float* zbuf   = (float*)(pair + N_EDGES);
        int*   cnt    = (int*)(zbuf + (size_t)N_NODES * ZD);
        int*   part   = cnt + N_NODES;
        int*   cursor = part + 128;

        (void)hipMemsetAsync(cnt, 0, N_NODES * sizeof(int), stream);
        hist<<<(N_EDGES + 255) / 256, 256, 0, stream>>>(dst, cnt);
        scan_part<<<NTILE, 1024, 0, stream>>>(cnt, part);
        scan_top<<<1, 128, 0, stream>>>(part);
        scan_local<<<NTILE, 1024, 0, stream>>>(cnt, part, cursor);
        permute_ids<<<(N_EDGES + 255) / 256, 256, 0, stream>>>(src, dst, cursor, pair);
        z_csr<<<2048, 256, 0, stream>>>(node_x, edge_x, z_init, W_pre, b_pre,
                                        cnt, cursor, pair, zbuf);
        h_upd<<<2048, 256, 0, stream>>>(node_x, W_upd, b_upd, zbuf, out);
    } else {
        // Fallback (~26 MB): S[N*64]f | degI[N]i
        float* S    = (float*)d_ws;
        int*   degI = (int*)(S + (size_t)N_NODES * ZD);
        (void)hipMemsetAsync(d_ws, 0,
            ((size_t)N_NODES * ZD + N_NODES) * sizeof(float), stream);
        edge_scatter<<<(int)(((long)N_EDGES * 64 + 255) / 256), 256, 0, stream>>>(
            node_x, edge_x, src, dst, S, degI);
        z_dense<<<2048, 256, 0, stream>>>(z_init, W_pre, b_pre, S, degI);
        h_upd<<<2048, 256, 0, stream>>>(node_x, W_upd, b_upd, S, out);
    }
}